// Round 3
// baseline (579.635 us; speedup 1.0000x reference)
//
#include <hip/hip_runtime.h>
#include <hip/hip_bf16.h>

// ---------------------------------------------------------------------------
// NaSwinAttention on MI355X.
// Static problem geometry:
//   T=10,H=45,W=80 -> N_VID=36000, D=512, HEADS=4, HD=128, TXT=64
//   windows: wt=5, wh=9, ww=16 ; nt=2, nh=5, nw=5 -> 50 windows x 720 tokens
//   window id  w = iw*10 + ih*2 + it   (it fastest)
//   pos in win p = dt*144 + dh*16 + dw
//   token      n = (it*5+dt)*3600 + (ih*9+dh)*80 + iw*16 + dw
//   seq per window = 720 + 64 txt = 784, padded to 832 (13*64)
// ---------------------------------------------------------------------------

typedef unsigned short u16;
typedef unsigned int   u32;
typedef float v4f __attribute__((ext_vector_type(4)));
typedef short v8s __attribute__((ext_vector_type(8)));
typedef short v4s __attribute__((ext_vector_type(4)));

#define N_VID    36000
#define MPAD     36096        // 282*128
#define DM       512
#define NW       50
#define WSZ      720
#define SEQ      784
#define SP       832          // padded seq (13*64)
#define QK_SCALE 0.08838834764831845f
#define L2THETA  13.287712379549449f   // log2(10000)

union U8 { uint4 u; u16 s[8]; };

__device__ __forceinline__ u16 f2b(float f) {
  u32 u = __builtin_bit_cast(u32, f);
  u32 r = (u + 0x7FFFu + ((u >> 16) & 1u)) >> 16;
  return (u16)r;
}
__device__ __forceinline__ float b2f(u16 h) {
  u32 u = ((u32)h) << 16;
  return __builtin_bit_cast(float, u);
}
// pack hi16(lo),hi16(hi) -> u32 (bf16 truncation pack, 1 instr)
__device__ __forceinline__ u32 pkhi(float lo, float hi) {
  return __builtin_amdgcn_perm(__builtin_bit_cast(u32, hi),
                               __builtin_bit_cast(u32, lo), 0x07060302u);
}

__device__ __forceinline__ void gload_lds16(const void* g, void* l) {
  __builtin_amdgcn_global_load_lds(
      (const __attribute__((address_space(1))) void*)g,
      (__attribute__((address_space(3))) void*)l,
      16, 0, 0);
}

// ---------------------------------------------------------------------------
// K0: fp32 -> bf16 convert, vid padded to MPAD rows (zeros), txt padded to 128.
__global__ __launch_bounds__(256) void k_convert(const float* __restrict__ vid,
                                                 const float* __restrict__ txt,
                                                 u16* __restrict__ vid_b,
                                                 u16* __restrict__ txt_b) {
  int id  = blockIdx.x * 256 + threadIdx.x;
  int row = id >> 6, oct = id & 63;
  U8 o;
  if (row < MPAD) {
    if (row < N_VID) {
      const float* s = vid + (size_t)row * DM + oct * 8;
      float4 a = *(const float4*)s, b = *(const float4*)(s + 4);
      o.s[0]=f2b(a.x); o.s[1]=f2b(a.y); o.s[2]=f2b(a.z); o.s[3]=f2b(a.w);
      o.s[4]=f2b(b.x); o.s[5]=f2b(b.y); o.s[6]=f2b(b.z); o.s[7]=f2b(b.w);
    } else { o.u = make_uint4(0,0,0,0); }
    *(uint4*)&vid_b[(size_t)row * DM + oct * 8] = o.u;
  } else {
    int tr = row - MPAD;
    if (tr >= 128) return;
    if (tr < 64) {
      const float* s = txt + (size_t)tr * DM + oct * 8;
      float4 a = *(const float4*)s, b = *(const float4*)(s + 4);
      o.s[0]=f2b(a.x); o.s[1]=f2b(a.y); o.s[2]=f2b(a.z); o.s[3]=f2b(a.w);
      o.s[4]=f2b(b.x); o.s[5]=f2b(b.y); o.s[6]=f2b(b.z); o.s[7]=f2b(b.w);
    } else { o.u = make_uint4(0,0,0,0); }
    *(uint4*)&txt_b[(size_t)tr * DM + oct * 8] = o.u;
  }
}

// ---------------------------------------------------------------------------
// K0b: weight transpose fp32 [K][N] -> bf16 [N][K]  (K always 512)
__global__ __launch_bounds__(256) void k_transw(const float* __restrict__ wqv,
                                                const float* __restrict__ wqt,
                                                const float* __restrict__ wov,
                                                u16* __restrict__ o0,
                                                u16* __restrict__ o1,
                                                u16* __restrict__ o2) {
  __shared__ u16 lt[64 * 72];
  int b = blockIdx.x, t = threadIdx.x;
  const float* src; u16* dst; int N; int tb;
  if (b < 192)      { src = wqv; dst = o0; N = 1536; tb = b; }
  else if (b < 384) { src = wqt; dst = o1; N = 1536; tb = b - 192; }
  else              { src = wov; dst = o2; N = 512;  tb = b - 384; }
  int kt = tb & 7, nt = tb >> 3;
  int k0 = kt * 64, n0 = nt * 64;
#pragma unroll
  for (int pass = 0; pass < 16; ++pass) {
    int kl = pass * 4 + (t >> 6), nl = t & 63;
    float v = src[(size_t)(k0 + kl) * N + n0 + nl];
    lt[nl * 72 + kl] = f2b(v);
  }
  __syncthreads();
#pragma unroll
  for (int pass = 0; pass < 2; ++pass) {
    int slot = pass * 256 + t;
    int nr = slot >> 3, ko = slot & 7;
    U8 o;
#pragma unroll
    for (int j = 0; j < 8; ++j) o.s[j] = lt[nr * 72 + ko * 8 + j];
    *(uint4*)&dst[(size_t)(n0 + nr) * 512 + k0 + ko * 8] = o.u;
  }
}

// ---------------------------------------------------------------------------
// K1: bf16 GEMM  C[M][N] = A[M][K] * Bt[N][K]^T   (m97-style 128x128 tile)
template <int F32OUT>
__global__ __launch_bounds__(256) void k_gemm(const u16* __restrict__ A,
                                              const u16* __restrict__ Bt,
                                              void* __restrict__ Cout,
                                              int M, int N, int K, int Mstore) {
  __shared__ u16 lA[128 * 32];
  __shared__ u16 lB[128 * 32];
  int t = threadIdx.x, wv = t >> 6, L = t & 63;
  int m0 = blockIdx.x * 128, n0 = blockIdx.y * 128;
  int wm = wv & 1, wn = wv >> 1;
  v4f acc[4][4] = {};
  const int kiters = K >> 5;
  const u16* ga = A + (size_t)(m0 + wv * 32 + (L >> 2)) * K + (L & 3) * 8;
  const u16* gb = Bt + (size_t)(n0 + wv * 32 + (L >> 2)) * K + (L & 3) * 8;
  u16* la = lA + (wv * 32) * 32;
  u16* lb = lB + (wv * 32) * 32;
  for (int kt = 0; kt < kiters; ++kt) {
    __syncthreads();
    gload_lds16(ga,                 la);
    gload_lds16(ga + (size_t)16 * K, la + 16 * 32);
    gload_lds16(gb,                 lb);
    gload_lds16(gb + (size_t)16 * K, lb + 16 * 32);
    ga += 32; gb += 32;
    __syncthreads();
    v8s af[4], bf[4];
#pragma unroll
    for (int i = 0; i < 4; ++i) {
      af[i] = *(const v8s*)&lA[(wm * 64 + i * 16 + (L & 15)) * 32 + (L >> 4) * 8];
      bf[i] = *(const v8s*)&lB[(wn * 64 + i * 16 + (L & 15)) * 32 + (L >> 4) * 8];
    }
#pragma unroll
    for (int i = 0; i < 4; ++i)
#pragma unroll
      for (int j = 0; j < 4; ++j)
        acc[i][j] = __builtin_amdgcn_mfma_f32_16x16x32_bf16(af[i], bf[j], acc[i][j], 0, 0, 0);
  }
#pragma unroll
  for (int i = 0; i < 4; ++i) {
#pragma unroll
    for (int r = 0; r < 4; ++r) {
      int row = m0 + wm * 64 + i * 16 + (L >> 4) * 4 + r;
      if (row < Mstore) {
#pragma unroll
        for (int j = 0; j < 4; ++j) {
          int col = n0 + wn * 64 + j * 16 + (L & 15);
          if (F32OUT) ((float*)Cout)[(size_t)row * N + col] = acc[i][j][r];
          else        ((u16*)Cout)[(size_t)row * N + col] = f2b(acc[i][j][r]);
        }
      }
    }
  }
}

// ---------------------------------------------------------------------------
// K2: RoPE + window gather (unchanged).
__global__ __launch_bounds__(256) void k_ropegather(const u16* __restrict__ qkv,
                                                    u16* __restrict__ Q,
                                                    u16* __restrict__ K,
                                                    u16* __restrict__ Vt) {
  __shared__ u16 lv[512 * 18];
  int t = threadIdx.x;
  int pt = blockIdx.x, w = blockIdx.y;
  int p_local = t >> 4;
  int p = pt * 16 + p_local;               // < 720
  int iw = w / 10; int r10 = w - iw * 10; int ih = r10 >> 1; int it = r10 & 1;
  int dt = p / 144; int rem = p - dt * 144; int dh = rem >> 4; int dw = rem & 15;
  int tt = it * 5 + dt, hh = ih * 9 + dh, wx = iw * 16 + dw;
  int n = tt * 3600 + hh * 80 + wx;
  const size_t qrow = (size_t)n * 1536;
#pragma unroll
  for (int it2 = 0; it2 < 12; ++it2) {
    int oct = it2 * 16 + (t & 15);
    int col = oct * 8;
    U8 x; x.u = *(const uint4*)&qkv[qrow + col];
    if (col < 1024) {                      // Q or K -> rope
      int cc = col & 511; int h = cc >> 7; int ch = cc & 127;
      int pos, i0; float dinv;
      if (ch < 32)      { pos = tt; i0 = ch >> 1;        dinv = 1.f / 32.f; }
      else if (ch < 80) { pos = hh; i0 = (ch - 32) >> 1; dinv = 1.f / 48.f; }
      else              { pos = wx; i0 = (ch - 80) >> 1; dinv = 1.f / 48.f; }
      bool isQ = col < 512;
      float sc = isQ ? QK_SCALE : 1.0f;
      U8 o;
#pragma unroll
      for (int pr = 0; pr < 4; ++pr) {
        float inv = exp2f(-2.f * (float)(i0 + pr) * dinv * L2THETA);
        float ang = (float)pos * inv;
        float s, c; __sincosf(ang, &s, &c);
        float x0 = b2f(x.s[2 * pr]), x1 = b2f(x.s[2 * pr + 1]);
        o.s[2 * pr]     = f2b((x0 * c - x1 * s) * sc);
        o.s[2 * pr + 1] = f2b((x1 * c + x0 * s) * sc);
      }
      u16* dst = isQ ? Q : K;
      *(uint4*)&dst[(((size_t)w * 4 + h) * SP + p) * 128 + ch] = o.u;
    } else {                               // V -> LDS for transpose
      int cv = col - 1024;
#pragma unroll
      for (int j = 0; j < 8; ++j) lv[(cv + j) * 18 + p_local] = x.s[j];
    }
  }
  __syncthreads();
#pragma unroll
  for (int it3 = 0; it3 < 4; ++it3) {
    int slot = it3 * 256 + t; int cv = slot >> 1; int half = slot & 1;
    U8 o;
#pragma unroll
    for (int j = 0; j < 8; ++j) o.s[j] = lv[cv * 18 + half * 8 + j];
    int h = cv >> 7, ch = cv & 127;
    *(uint4*)&Vt[(((size_t)w * 4 + h) * 128 + ch) * SP + pt * 16 + half * 8] = o.u;
  }
}

// ---------------------------------------------------------------------------
// K3: broadcast txt tokens into every window at positions 720..783 (unchanged).
__global__ __launch_bounds__(256) void k_txtfill(const u16* __restrict__ qkvt,
                                                 u16* __restrict__ Q,
                                                 u16* __restrict__ K,
                                                 u16* __restrict__ Vt) {
  int id = blockIdx.x * 256 + threadIdx.x;
  if (blockIdx.x < 800) {
    int c8 = id & 15, i = (id >> 4) & 63, wh = id >> 10;   // wh 0..199
    int h = wh & 3; int ch = c8 * 8;
    U8 q, k;
    q.u = *(const uint4*)&qkvt[(size_t)i * 1536 + h * 128 + ch];
    k.u = *(const uint4*)&qkvt[(size_t)i * 1536 + 512 + h * 128 + ch];
#pragma unroll
    for (int j = 0; j < 8; ++j) q.s[j] = f2b(b2f(q.s[j]) * QK_SCALE);
    int p = WSZ + i;
    size_t base = ((size_t)wh * SP + p) * 128 + ch;
    *(uint4*)&Q[base] = q.u;
    *(uint4*)&K[base] = k.u;
  } else {
    int id2 = id - 800 * 256;
    if (id2 >= 25600) return;
    int ch = id2 & 127; int wh = id2 >> 7; int h = wh & 3;
    u16 vals[64];
#pragma unroll
    for (int i = 0; i < 64; ++i)
      vals[i] = qkvt[(size_t)i * 1536 + 1024 + h * 128 + ch];
    size_t rb = ((size_t)wh * 128 + ch) * SP + WSZ;
#pragma unroll
    for (int j = 0; j < 8; ++j) {
      U8 o;
#pragma unroll
      for (int m = 0; m < 8; ++m) o.s[m] = vals[j * 8 + m];
      *(uint4*)&Vt[rb + j * 8] = o.u;
    }
  }
}

// ---------------------------------------------------------------------------
// K4: flash attention, transposed-S formulation. Per (w,h,qt): 4 waves x 32 q.
//  S^T = mfma(K_frag, Q_frag): C-layout col=q, row=key (=quad*4+r per nb).
//  P^T kept in registers; PV computed as O^T = V^T P^T with a permuted
//  contraction order sigma(quad,j) = j<4 ? quad*4+j : 16+quad*4+(j-4), so the
//  B-operand (P^T) packs straight from own-lane regs (v_perm truncation) and
//  the A-operand (V^T) is two ds_read_b64 from lV. No P LDS round trip.
//  784 = 12*64+16 -> key masking is wave-uniform: kt==12 && nbk>0 only.
//  O^T layout: lane holds 4 consecutive channels -> 8B epilogue stores.
//  Grid: flat 1400, XCD-swizzled so all 7 qt blocks of one (w,h) share id%8.
__global__ __launch_bounds__(256) void k_attn(const u16* __restrict__ Q,
                                              const u16* __restrict__ Kb,
                                              const u16* __restrict__ Vt,
                                              u16* __restrict__ outr,
                                              float* __restrict__ txt_acc) {
  __shared__ u16 lK[4 * 64 * 32];     // [kc4][key 64][ch 32]
  __shared__ u16 lV[2 * 128 * 32];    // [kc2][ch 128][pos 32]
  int t = threadIdx.x, wv = t >> 6, L = t & 63;
  // XCD swizzle decode
  int id = blockIdx.x;
  int xcd = id & 7, sidx = id >> 3;
  int whg = sidx / 7;  int qt = sidx - whg * 7;
  int wh = whg * 8 + xcd;
  int w = wh >> 2, h = wh & 3;
  size_t whq = ((size_t)wh) * SP * 128;
  int q0 = qt * 128 + wv * 32;
  if (q0 > 800) q0 = 800;             // tail: rows 800..831 are pad, no stores
  int colL = L & 15, quad = L >> 4;
  v8s qf[2][4];
#pragma unroll
  for (int s = 0; s < 2; ++s) {
    const u16* qp = Q + whq + (size_t)(q0 + s * 16 + colL) * 128 + quad * 8;
#pragma unroll
    for (int kc = 0; kc < 4; ++kc) qf[s][kc] = *(const v8s*)(qp + kc * 32);
  }
  float li[2] = {0.f, 0.f};
  v4f O[2][8] = {};

  for (int kt = 0; kt < 13; ++kt) {
    __syncthreads();
#pragma unroll
    for (int pass = 0; pass < 4; ++pass) {
      int cr = wv * 64 + pass * 16 + (L >> 2);
      int kc = cr >> 6, row = cr & 63;          // K tile: [kc][row][32]
      gload_lds16(Kb + whq + (size_t)(kt * 64 + row) * 128 + kc * 32 + (L & 3) * 8,
                  (u16*)lK + (size_t)(wv * 64 + pass * 16) * 32);
      int kc2 = cr >> 7, ch = cr & 127;          // V tile: [kc2][ch][32]
      gload_lds16(Vt + whq + (size_t)ch * SP + kt * 64 + kc2 * 32 + (L & 3) * 8,
                  (u16*)lV + (size_t)(wv * 64 + pass * 16) * 32);
    }
    __syncthreads();

    // S^T = K Q^T  (scale pre-folded into Q); col=q, row=key
    v4f ST[2][4] = {};
#pragma unroll
    for (int kc = 0; kc < 4; ++kc) {
#pragma unroll
      for (int nbk = 0; nbk < 4; ++nbk) {
        v8s kf = *(const v8s*)&lK[(kc * 64 + nbk * 16 + colL) * 32 + quad * 8];
        ST[0][nbk] = __builtin_amdgcn_mfma_f32_16x16x32_bf16(kf, qf[0][kc], ST[0][nbk], 0, 0, 0);
        ST[1][nbk] = __builtin_amdgcn_mfma_f32_16x16x32_bf16(kf, qf[1][kc], ST[1][nbk], 0, 0, 0);
      }
    }

    // exp (wave-uniform masking: only kt==12, nbk>0 invalid), truncate to
    // bf16, accumulate li from truncated values, pack B-frags (P^T).
    union { v8s v; u32 wd[4]; } Bf[2][2];   // [kc2][s]
#pragma unroll
    for (int s = 0; s < 2; ++s) {
#pragma unroll
      for (int nbk = 0; nbk < 4; ++nbk) {
        float ev[4];
        if (kt * 64 + nbk * 16 < SEQ) {
#pragma unroll
          for (int r = 0; r < 4; ++r) {
            float e = __expf(ST[s][nbk][r]);
            u32 tb = __builtin_bit_cast(u32, e) & 0xFFFF0000u;
            float tf = __builtin_bit_cast(float, tb);
            li[s] += tf;
            ev[r] = tf;
          }
        } else {
#pragma unroll
          for (int r = 0; r < 4; ++r) ev[r] = 0.f;
        }
        Bf[nbk >> 1][s].wd[(nbk & 1) * 2 + 0] = pkhi(ev[0], ev[1]);
        Bf[nbk >> 1][s].wd[(nbk & 1) * 2 + 1] = pkhi(ev[2], ev[3]);
      }
    }

    // O^T += V^T P^T  (permuted k-order; A from lV, B from regs)
#pragma unroll
    for (int kc2 = 0; kc2 < 2; ++kc2) {
#pragma unroll
      for (int nbo = 0; nbo < 8; ++nbo) {
        const u16* vp = &lV[(kc2 * 128 + nbo * 16 + colL) * 32 + quad * 4];
        v4s lo = *(const v4s*)vp;
        v4s hi = *(const v4s*)(vp + 16);
        v8s af = __builtin_shufflevector(lo, hi, 0, 1, 2, 3, 4, 5, 6, 7);
        O[0][nbo] = __builtin_amdgcn_mfma_f32_16x16x32_bf16(af, Bf[kc2][0].v, O[0][nbo], 0, 0, 0);
        O[1][nbo] = __builtin_amdgcn_mfma_f32_16x16x32_bf16(af, Bf[kc2][1].v, O[1][nbo], 0, 0, 0);
      }
    }
  }

  // li: reduce across quads (lanes c, c+16, c+32, c+48)
  float linv[2];
#pragma unroll
  for (int s = 0; s < 2; ++s) {
    float v = li[s];
    v += __shfl_xor(v, 16);
    v += __shfl_xor(v, 32);
    linv[s] = 1.f / v;
  }

  // epilogue: lane holds channels nbo*16+quad*4+{0..3} of q row (q0+s*16+colL)
  int iw = w / 10; int r10 = w - iw * 10; int ih = r10 >> 1; int it = r10 & 1;
#pragma unroll
  for (int s = 0; s < 2; ++s) {
    int p = q0 + s * 16 + colL;
    if (p < WSZ) {
      int dt = p / 144; int rem = p - dt * 144; int dh = rem >> 4; int dw = rem & 15;
      int n = (it * 5 + dt) * 3600 + (ih * 9 + dh) * 80 + iw * 16 + dw;
      size_t rowbase = (size_t)n * DM + h * 128 + quad * 4;
#pragma unroll
      for (int nbo = 0; nbo < 8; ++nbo) {
        uint2 st;
        st.x = (u32)f2b(O[s][nbo][0] * linv[s]) | ((u32)f2b(O[s][nbo][1] * linv[s]) << 16);
        st.y = (u32)f2b(O[s][nbo][2] * linv[s]) | ((u32)f2b(O[s][nbo][3] * linv[s]) << 16);
        *(uint2*)&outr[rowbase + nbo * 16] = st;
      }
    } else if (p < SEQ) {
      size_t rb = (size_t)(p - WSZ) * DM + h * 128 + quad * 4;
#pragma unroll
      for (int nbo = 0; nbo < 8; ++nbo)
#pragma unroll
        for (int r = 0; r < 4; ++r)
          atomicAdd(&txt_acc[rb + nbo * 16 + r], O[s][nbo][r] * linv[s] * 0.02f);
    }
  }
}

// ---------------------------------------------------------------------------
// K5: txt out rows (64x512 = txt_acc @ w_out_txt), full fp32.
__global__ __launch_bounds__(256) void k_txtout(const float* __restrict__ acc,
                                                const float* __restrict__ wo,
                                                float* __restrict__ ob) {
  int r = blockIdx.x, t = threadIdx.x;
  float s0 = 0.f, s1 = 0.f;
  for (int k = 0; k < 512; ++k) {
    float a = acc[r * 512 + k];
    s0 = fmaf(a, wo[k * 512 + t], s0);
    s1 = fmaf(a, wo[k * 512 + t + 256], s1);
  }
  ob[(size_t)r * 512 + t] = s0;
  ob[(size_t)r * 512 + t + 256] = s1;
}

// ---------------------------------------------------------------------------
extern "C" void kernel_launch(void* const* d_in, const int* in_sizes, int n_in,
                              void* d_out, int out_size, void* d_ws, size_t ws_size,
                              hipStream_t stream) {
  const float* vid       = (const float*)d_in[0];
  const float* txt       = (const float*)d_in[1];
  const float* w_qkv_vid = (const float*)d_in[2];
  const float* w_qkv_txt = (const float*)d_in[3];
  const float* w_out_vid = (const float*)d_in[4];
  const float* w_out_txt = (const float*)d_in[5];
  float* out = (float*)d_out;
  char* ws = (char*)d_ws;

  size_t off = 0;
  u16* vid_b   = (u16*)(ws + off); off += (size_t)MPAD * DM * 2;       // reused as out_rows
  u16* txt_b   = (u16*)(ws + off); off += 128 * DM * 2;
  u16* wt_qv   = (u16*)(ws + off); off += 1536 * 512 * 2;
  u16* wt_qt   = (u16*)(ws + off); off += 1536 * 512 * 2;
  u16* wt_ov   = (u16*)(ws + off); off += 512 * 512 * 2;
  u16* qkv_v   = (u16*)(ws + off); off += (size_t)MPAD * 1536 * 2;
  u16* qkv_t   = (u16*)(ws + off); off += 128 * 1536 * 2;
  u16* Qb      = (u16*)(ws + off); off += (size_t)NW * 4 * SP * 128 * 2;
  u16* Kb      = (u16*)(ws + off); off += (size_t)NW * 4 * SP * 128 * 2;
  u16* Vtb     = (u16*)(ws + off); off += (size_t)NW * 4 * 128 * SP * 2;
  float* tacc  = (float*)(ws + off); off += 64 * 512 * 4;
  u16* out_rows = vid_b;   // alias: vid_b dead after QKV GEMM

  hipMemsetAsync(tacc, 0, 64 * 512 * 4, stream);

  k_convert<<<9056, 256, 0, stream>>>(vid, txt, vid_b, txt_b);
  k_transw<<<448, 256, 0, stream>>>(w_qkv_vid, w_qkv_txt, w_out_vid, wt_qv, wt_qt, wt_ov);

  k_gemm<0><<<dim3(282, 12), 256, 0, stream>>>(vid_b, wt_qv, qkv_v, MPAD, 1536, 512, MPAD);
  k_gemm<0><<<dim3(1, 12), 256, 0, stream>>>(txt_b, wt_qt, qkv_t, 128, 1536, 512, 128);

  k_ropegather<<<dim3(45, 50), 256, 0, stream>>>(qkv_v, Qb, Kb, Vtb);
  k_txtfill<<<900, 256, 0, stream>>>(qkv_t, Qb, Kb, Vtb);

  k_attn<<<1400, 256, 0, stream>>>(Qb, Kb, Vtb, out_rows, tacc);

  k_gemm<1><<<dim3(282, 4), 256, 0, stream>>>(out_rows, wt_ov, out, MPAD, 512, 512, N_VID);
  k_txtout<<<64, 256, 0, stream>>>(tacc, w_out_txt, out + (size_t)N_VID * DM);
}

// Round 4
// 470.353 us; speedup vs baseline: 1.2323x; 1.2323x over previous
//
#include <hip/hip_runtime.h>
#include <hip/hip_bf16.h>

// ---------------------------------------------------------------------------
// NaSwinAttention on MI355X.
// Static problem geometry:
//   T=10,H=45,W=80 -> N_VID=36000, D=512, HEADS=4, HD=128, TXT=64
//   windows: wt=5, wh=9, ww=16 ; nt=2, nh=5, nw=5 -> 50 windows x 720 tokens
//   window id  w = iw*10 + ih*2 + it   (it fastest)
//   pos in win p = dt*144 + dh*16 + dw
//   token      n = (it*5+dt)*3600 + (ih*9+dh)*80 + iw*16 + dw
//   seq per window = 720 + 64 txt = 784, padded to 832 (13*64)
//
// Vt global layout is POSITION-PERMUTED: within each 32-aligned pos chunk,
// physical index e holds logical pos (e>>3)*4 + (e&3) + ((e>>2)&1)*16, so
// k_attn's b128 read at phys [quad*8..+7] yields logical keys
// {quad*4+0..3, 16+quad*4+0..3} = the sigma-order used by the register-P
// PV contraction. Inverse (4-aligned run start l0):
//   phys = (l0 & ~31) + ((l0&15)>>2)*8 + ((l0>>4)&1)*4
// ---------------------------------------------------------------------------

typedef unsigned short u16;
typedef unsigned int   u32;
typedef float v4f __attribute__((ext_vector_type(4)));
typedef short v8s __attribute__((ext_vector_type(8)));

#define N_VID    36000
#define MPAD     36096        // 282*128
#define DM       512
#define NW       50
#define WSZ      720
#define SEQ      784
#define SP       832          // padded seq (13*64)
#define QK_SCALE 0.08838834764831845f
#define L2THETA  13.287712379549449f   // log2(10000)

union U8 { uint4 u; u16 s[8]; };

__device__ __forceinline__ u16 f2b(float f) {
  u32 u = __builtin_bit_cast(u32, f);
  u32 r = (u + 0x7FFFu + ((u >> 16) & 1u)) >> 16;
  return (u16)r;
}
__device__ __forceinline__ float b2f(u16 h) {
  u32 u = ((u32)h) << 16;
  return __builtin_bit_cast(float, u);
}
// pack hi16(lo),hi16(hi) -> u32 (bf16 truncation pack, 1 instr)
__device__ __forceinline__ u32 pkhi(float lo, float hi) {
  return __builtin_amdgcn_perm(__builtin_bit_cast(u32, hi),
                               __builtin_bit_cast(u32, lo), 0x07060302u);
}
// physical index of a 4-aligned logical-position run start (Vt permutation)
__device__ __forceinline__ int vperm4(int l0) {
  return (l0 & ~31) + (((l0 & 15) >> 2) << 3) + (((l0 >> 4) & 1) << 2);
}

__device__ __forceinline__ void gload_lds16(const void* g, void* l) {
  __builtin_amdgcn_global_load_lds(
      (const __attribute__((address_space(1))) void*)g,
      (__attribute__((address_space(3))) void*)l,
      16, 0, 0);
}

// ---------------------------------------------------------------------------
// K0: fused prep. blocks 0..9055: fp32->bf16 convert (vid padded to MPAD,
// txt padded to 128). blocks 9056..9503: weight transpose fp32[K][N]->bf16[N][K].
__global__ __launch_bounds__(256) void k_prep(const float* __restrict__ vid,
                                              const float* __restrict__ txt,
                                              u16* __restrict__ vid_b,
                                              u16* __restrict__ txt_b,
                                              const float* __restrict__ wqv,
                                              const float* __restrict__ wqt,
                                              const float* __restrict__ wov,
                                              u16* __restrict__ o0,
                                              u16* __restrict__ o1,
                                              u16* __restrict__ o2) {
  __shared__ u16 lt[64 * 72];
  int t = threadIdx.x;
  if (blockIdx.x < 9056) {
    int id  = blockIdx.x * 256 + t;
    int row = id >> 6, oct = id & 63;
    U8 o;
    if (row < MPAD) {
      if (row < N_VID) {
        const float* s = vid + (size_t)row * DM + oct * 8;
        float4 a = *(const float4*)s, b = *(const float4*)(s + 4);
        o.s[0]=f2b(a.x); o.s[1]=f2b(a.y); o.s[2]=f2b(a.z); o.s[3]=f2b(a.w);
        o.s[4]=f2b(b.x); o.s[5]=f2b(b.y); o.s[6]=f2b(b.z); o.s[7]=f2b(b.w);
      } else { o.u = make_uint4(0,0,0,0); }
      *(uint4*)&vid_b[(size_t)row * DM + oct * 8] = o.u;
    } else {
      int tr = row - MPAD;
      if (tr >= 128) return;
      if (tr < 64) {
        const float* s = txt + (size_t)tr * DM + oct * 8;
        float4 a = *(const float4*)s, b = *(const float4*)(s + 4);
        o.s[0]=f2b(a.x); o.s[1]=f2b(a.y); o.s[2]=f2b(a.z); o.s[3]=f2b(a.w);
        o.s[4]=f2b(b.x); o.s[5]=f2b(b.y); o.s[6]=f2b(b.z); o.s[7]=f2b(b.w);
      } else { o.u = make_uint4(0,0,0,0); }
      *(uint4*)&txt_b[(size_t)tr * DM + oct * 8] = o.u;
    }
    return;
  }
  // ---- transpose branch ----
  int b = blockIdx.x - 9056;
  const float* src; u16* dst; int N; int tb;
  if (b < 192)      { src = wqv; dst = o0; N = 1536; tb = b; }
  else if (b < 384) { src = wqt; dst = o1; N = 1536; tb = b - 192; }
  else              { src = wov; dst = o2; N = 512;  tb = b - 384; }
  int kt = tb & 7, nt = tb >> 3;
  int k0 = kt * 64, n0 = nt * 64;
#pragma unroll
  for (int pass = 0; pass < 16; ++pass) {
    int kl = pass * 4 + (t >> 6), nl = t & 63;
    float v = src[(size_t)(k0 + kl) * N + n0 + nl];
    lt[nl * 72 + kl] = f2b(v);
  }
  __syncthreads();
#pragma unroll
  for (int pass = 0; pass < 2; ++pass) {
    int slot = pass * 256 + t;
    int nr = slot >> 3, ko = slot & 7;
    U8 o;
#pragma unroll
    for (int j = 0; j < 8; ++j) o.s[j] = lt[nr * 72 + ko * 8 + j];
    *(uint4*)&dst[(size_t)(n0 + nr) * 512 + k0 + ko * 8] = o.u;
  }
}

// ---------------------------------------------------------------------------
// GEMM body: C[M][N] = A[M][K] * Bt[N][K]^T  (m97-style 128x128 tile)
template <int F32OUT>
__device__ __forceinline__ void gemm_body(const u16* __restrict__ A,
                                          const u16* __restrict__ Bt,
                                          void* __restrict__ Cout,
                                          int N, int K, int Mstore,
                                          int m0, int n0) {
  __shared__ u16 lA[128 * 32];
  __shared__ u16 lB[128 * 32];
  int t = threadIdx.x, wv = t >> 6, L = t & 63;
  int wm = wv & 1, wn = wv >> 1;
  v4f acc[4][4] = {};
  const int kiters = K >> 5;
  const u16* ga = A + (size_t)(m0 + wv * 32 + (L >> 2)) * K + (L & 3) * 8;
  const u16* gb = Bt + (size_t)(n0 + wv * 32 + (L >> 2)) * K + (L & 3) * 8;
  u16* la = lA + (wv * 32) * 32;
  u16* lb = lB + (wv * 32) * 32;
  for (int kt = 0; kt < kiters; ++kt) {
    __syncthreads();
    gload_lds16(ga,                 la);
    gload_lds16(ga + (size_t)16 * K, la + 16 * 32);
    gload_lds16(gb,                 lb);
    gload_lds16(gb + (size_t)16 * K, lb + 16 * 32);
    ga += 32; gb += 32;
    __syncthreads();
    v8s af[4], bf[4];
#pragma unroll
    for (int i = 0; i < 4; ++i) {
      af[i] = *(const v8s*)&lA[(wm * 64 + i * 16 + (L & 15)) * 32 + (L >> 4) * 8];
      bf[i] = *(const v8s*)&lB[(wn * 64 + i * 16 + (L & 15)) * 32 + (L >> 4) * 8];
    }
#pragma unroll
    for (int i = 0; i < 4; ++i)
#pragma unroll
      for (int j = 0; j < 4; ++j)
        acc[i][j] = __builtin_amdgcn_mfma_f32_16x16x32_bf16(af[i], bf[j], acc[i][j], 0, 0, 0);
  }
#pragma unroll
  for (int i = 0; i < 4; ++i) {
#pragma unroll
    for (int r = 0; r < 4; ++r) {
      int row = m0 + wm * 64 + i * 16 + (L >> 4) * 4 + r;
      if (row < Mstore) {
#pragma unroll
        for (int j = 0; j < 4; ++j) {
          int col = n0 + wn * 64 + j * 16 + (L & 15);
          if (F32OUT) ((float*)Cout)[(size_t)row * N + col] = acc[i][j][r];
          else        ((u16*)Cout)[(size_t)row * N + col] = f2b(acc[i][j][r]);
        }
      }
    }
  }
}

// K1: QKV GEMM, vid (y<12) + txt (y==12, x<12) fused in one dispatch.
__global__ __launch_bounds__(256) void k_gemm_qkv(const u16* __restrict__ vid_b,
                                                  const u16* __restrict__ wt_qv,
                                                  u16* __restrict__ qkv_v,
                                                  const u16* __restrict__ txt_b,
                                                  const u16* __restrict__ wt_qt,
                                                  u16* __restrict__ qkv_t) {
  if (blockIdx.y < 12) {
    gemm_body<0>(vid_b, wt_qv, qkv_v, 1536, 512, MPAD, blockIdx.x * 128, blockIdx.y * 128);
  } else {
    if (blockIdx.x >= 12) return;
    gemm_body<0>(txt_b, wt_qt, qkv_t, 1536, 512, 128, 0, blockIdx.x * 128);
  }
}

// ---------------------------------------------------------------------------
// K2: RoPE + window gather (x<45) fused with txt broadcast fill (x>=45).
// Vt written in the position-permuted layout (see header comment).
__global__ __launch_bounds__(256) void k_ropegather(const u16* __restrict__ qkv,
                                                    const u16* __restrict__ qkvt,
                                                    u16* __restrict__ Q,
                                                    u16* __restrict__ K,
                                                    u16* __restrict__ Vt) {
  __shared__ u16 lv[512 * 18];
  int t = threadIdx.x;
  int w = blockIdx.y;
  if (blockIdx.x >= 45) {
    // ---- txt fill for window w: 4 blocks x 256 threads = 1024 ----
    int tb = (blockIdx.x - 45) * 256 + t;
#pragma unroll
    for (int k = 0; k < 4; ++k) {           // Q/K octets
      int o = tb * 4 + k;
      int h = o >> 10, p64 = (o >> 4) & 63, c8 = o & 15;
      U8 q, kk;
      q.u  = *(const uint4*)&qkvt[(size_t)p64 * 1536 + h * 128 + c8 * 8];
      kk.u = *(const uint4*)&qkvt[(size_t)p64 * 1536 + 512 + h * 128 + c8 * 8];
#pragma unroll
      for (int j = 0; j < 8; ++j) q.s[j] = f2b(b2f(q.s[j]) * QK_SCALE);
      size_t base = (((size_t)w * 4 + h) * SP + WSZ + p64) * 128 + c8 * 8;
      *(uint4*)&Q[base] = q.u;
      *(uint4*)&K[base] = kk.u;
    }
#pragma unroll
    for (int k = 0; k < 8; ++k) {           // V runs of 4 (permuted layout)
      int vr = tb * 8 + k;
      int h = vr >> 11, ch = (vr >> 4) & 127, run = vr & 15;
      int l0 = WSZ + run * 4;
      uint2 o;
      u16* os = (u16*)&o;
#pragma unroll
      for (int j = 0; j < 4; ++j)
        os[j] = qkvt[(size_t)(l0 - WSZ + j) * 1536 + 1024 + h * 128 + ch];
      *(uint2*)&Vt[(((size_t)w * 4 + h) * 128 + ch) * SP + vperm4(l0)] = o;
    }
    return;
  }
  // ---- rope + gather ----
  int pt = blockIdx.x;
  int p_local = t >> 4;
  int p = pt * 16 + p_local;               // < 720
  int iw = w / 10; int r10 = w - iw * 10; int ih = r10 >> 1; int it = r10 & 1;
  int dt = p / 144; int rem = p - dt * 144; int dh = rem >> 4; int dw = rem & 15;
  int tt = it * 5 + dt, hh = ih * 9 + dh, wx = iw * 16 + dw;
  int n = tt * 3600 + hh * 80 + wx;
  const size_t qrow = (size_t)n * 1536;
#pragma unroll
  for (int it2 = 0; it2 < 12; ++it2) {
    int oct = it2 * 16 + (t & 15);
    int col = oct * 8;
    U8 x; x.u = *(const uint4*)&qkv[qrow + col];
    if (col < 1024) {                      // Q or K -> rope
      int cc = col & 511; int h = cc >> 7; int ch = cc & 127;
      int pos, i0; float dinv;
      if (ch < 32)      { pos = tt; i0 = ch >> 1;        dinv = 1.f / 32.f; }
      else if (ch < 80) { pos = hh; i0 = (ch - 32) >> 1; dinv = 1.f / 48.f; }
      else              { pos = wx; i0 = (ch - 80) >> 1; dinv = 1.f / 48.f; }
      bool isQ = col < 512;
      float sc = isQ ? QK_SCALE : 1.0f;
      U8 o;
#pragma unroll
      for (int pr = 0; pr < 4; ++pr) {
        float inv = exp2f(-2.f * (float)(i0 + pr) * dinv * L2THETA);
        float ang = (float)pos * inv;
        float s, c; __sincosf(ang, &s, &c);
        float x0 = b2f(x.s[2 * pr]), x1 = b2f(x.s[2 * pr + 1]);
        o.s[2 * pr]     = f2b((x0 * c - x1 * s) * sc);
        o.s[2 * pr + 1] = f2b((x1 * c + x0 * s) * sc);
      }
      u16* dst = isQ ? Q : K;
      *(uint4*)&dst[(((size_t)w * 4 + h) * SP + p) * 128 + ch] = o.u;
    } else {                               // V -> LDS for transpose
      int cv = col - 1024;
#pragma unroll
      for (int j = 0; j < 8; ++j) lv[(cv + j) * 18 + p_local] = x.s[j];
    }
  }
  __syncthreads();
#pragma unroll
  for (int it3 = 0; it3 < 4; ++it3) {
    int slot = it3 * 256 + t; int cv = slot >> 1; int half = slot & 1;
    U8 o;
#pragma unroll
    for (int j = 0; j < 8; ++j) o.s[j] = lv[cv * 18 + half * 8 + j];
    int h = cv >> 7, ch = cv & 127;
    int P0 = pt * 16 + half * 8;           // logical pos run start (8-aligned)
    size_t base = (((size_t)w * 4 + h) * 128 + ch) * SP;
    *(uint2*)&Vt[base + vperm4(P0)]     = make_uint2(o.u.x, o.u.y);
    *(uint2*)&Vt[base + vperm4(P0 + 4)] = make_uint2(o.u.z, o.u.w);
  }
}

// ---------------------------------------------------------------------------
// K4: flash attention, transposed-S formulation. Per (w,h,qt): 4 waves x 32 q.
//  S^T = mfma(K_frag, Q_frag): C-layout col=q, row=key.
//  P^T packed from own-lane regs (v_perm truncation); PV contraction uses
//  sigma(quad,j) = j<4 ? quad*4+j : 16+quad*4+(j-4); the A-operand (V^T) is a
//  single conflict-floor ds_read_b128 because Vt is stored position-permuted.
//  784 = 12*64+16 -> key masking is wave-uniform: kt==12 && nbk>0 only.
//  Grid: flat 1400, XCD-swizzled so all 7 qt blocks of one (w,h) share id%8.
__global__ __launch_bounds__(256) void k_attn(const u16* __restrict__ Q,
                                              const u16* __restrict__ Kb,
                                              const u16* __restrict__ Vt,
                                              u16* __restrict__ outr,
                                              float* __restrict__ txt_acc) {
  __shared__ u16 lK[4 * 64 * 32];     // [kc4][key 64][ch 32]
  __shared__ u16 lV[2 * 128 * 32];    // [kc2][ch 128][perm-pos 32]
  int t = threadIdx.x, wv = t >> 6, L = t & 63;
  int id = blockIdx.x;
  int xcd = id & 7, sidx = id >> 3;
  int whg = sidx / 7;  int qt = sidx - whg * 7;
  int wh = whg * 8 + xcd;
  int w = wh >> 2, h = wh & 3;
  size_t whq = ((size_t)wh) * SP * 128;
  int q0 = qt * 128 + wv * 32;
  if (q0 > 800) q0 = 800;             // tail: rows 800..831 are pad, no stores
  int colL = L & 15, quad = L >> 4;
  v8s qf[2][4];
#pragma unroll
  for (int s = 0; s < 2; ++s) {
    const u16* qp = Q + whq + (size_t)(q0 + s * 16 + colL) * 128 + quad * 8;
#pragma unroll
    for (int kc = 0; kc < 4; ++kc) qf[s][kc] = *(const v8s*)(qp + kc * 32);
  }
  float li[2] = {0.f, 0.f};
  v4f O[2][8] = {};

  for (int kt = 0; kt < 13; ++kt) {
    __syncthreads();
#pragma unroll
    for (int pass = 0; pass < 4; ++pass) {
      int cr = wv * 64 + pass * 16 + (L >> 2);
      int kc = cr >> 6, row = cr & 63;          // K tile: [kc][row][32]
      gload_lds16(Kb + whq + (size_t)(kt * 64 + row) * 128 + kc * 32 + (L & 3) * 8,
                  (u16*)lK + (size_t)(wv * 64 + pass * 16) * 32);
      int kc2 = cr >> 7, ch = cr & 127;          // V tile: [kc2][ch][32]
      gload_lds16(Vt + whq + (size_t)ch * SP + kt * 64 + kc2 * 32 + (L & 3) * 8,
                  (u16*)lV + (size_t)(wv * 64 + pass * 16) * 32);
    }
    __syncthreads();

    // S^T = K Q^T  (scale pre-folded into Q); col=q, row=key
    v4f ST[2][4] = {};
#pragma unroll
    for (int kc = 0; kc < 4; ++kc) {
#pragma unroll
      for (int nbk = 0; nbk < 4; ++nbk) {
        v8s kf = *(const v8s*)&lK[(kc * 64 + nbk * 16 + colL) * 32 + quad * 8];
        ST[0][nbk] = __builtin_amdgcn_mfma_f32_16x16x32_bf16(kf, qf[0][kc], ST[0][nbk], 0, 0, 0);
        ST[1][nbk] = __builtin_amdgcn_mfma_f32_16x16x32_bf16(kf, qf[1][kc], ST[1][nbk], 0, 0, 0);
      }
    }

    // exp (wave-uniform masking: only kt==12, nbk>0 invalid), truncate to
    // bf16, accumulate li from truncated values, pack B-frags (P^T).
    union { v8s v; u32 wd[4]; } Bf[2][2];   // [kc2][s]
#pragma unroll
    for (int s = 0; s < 2; ++s) {
#pragma unroll
      for (int nbk = 0; nbk < 4; ++nbk) {
        float ev[4];
        if (kt * 64 + nbk * 16 < SEQ) {
#pragma unroll
          for (int r = 0; r < 4; ++r) {
            float e = __expf(ST[s][nbk][r]);
            u32 tb = __builtin_bit_cast(u32, e) & 0xFFFF0000u;
            float tf = __builtin_bit_cast(float, tb);
            li[s] += tf;
            ev[r] = tf;
          }
        } else {
#pragma unroll
          for (int r = 0; r < 4; ++r) ev[r] = 0.f;
        }
        Bf[nbk >> 1][s].wd[(nbk & 1) * 2 + 0] = pkhi(ev[0], ev[1]);
        Bf[nbk >> 1][s].wd[(nbk & 1) * 2 + 1] = pkhi(ev[2], ev[3]);
      }
    }

    // O^T += V^T P^T  (sigma k-order; A one b128 from permuted lV, B from regs)
#pragma unroll
    for (int kc2 = 0; kc2 < 2; ++kc2) {
#pragma unroll
      for (int nbo = 0; nbo < 8; ++nbo) {
        v8s af = *(const v8s*)&lV[(kc2 * 128 + nbo * 16 + colL) * 32 + quad * 8];
        O[0][nbo] = __builtin_amdgcn_mfma_f32_16x16x32_bf16(af, Bf[kc2][0].v, O[0][nbo], 0, 0, 0);
        O[1][nbo] = __builtin_amdgcn_mfma_f32_16x16x32_bf16(af, Bf[kc2][1].v, O[1][nbo], 0, 0, 0);
      }
    }
  }

  // li: reduce across quads (lanes c, c+16, c+32, c+48)
  float linv[2];
#pragma unroll
  for (int s = 0; s < 2; ++s) {
    float v = li[s];
    v += __shfl_xor(v, 16);
    v += __shfl_xor(v, 32);
    linv[s] = 1.f / v;
  }

  // epilogue: lane holds channels nbo*16+quad*4+{0..3} of q row (q0+s*16+colL)
  int iw = w / 10; int r10 = w - iw * 10; int ih = r10 >> 1; int it = r10 & 1;
#pragma unroll
  for (int s = 0; s < 2; ++s) {
    int p = q0 + s * 16 + colL;
    if (p < WSZ) {
      int dt = p / 144; int rem = p - dt * 144; int dh = rem >> 4; int dw = rem & 15;
      int n = (it * 5 + dt) * 3600 + (ih * 9 + dh) * 80 + iw * 16 + dw;
      size_t rowbase = (size_t)n * DM + h * 128 + quad * 4;
#pragma unroll
      for (int nbo = 0; nbo < 8; ++nbo) {
        uint2 st;
        st.x = (u32)f2b(O[s][nbo][0] * linv[s]) | ((u32)f2b(O[s][nbo][1] * linv[s]) << 16);
        st.y = (u32)f2b(O[s][nbo][2] * linv[s]) | ((u32)f2b(O[s][nbo][3] * linv[s]) << 16);
        *(uint2*)&outr[rowbase + nbo * 16] = st;
      }
    } else if (p < SEQ) {
      size_t rb = (size_t)(p - WSZ) * DM + h * 128 + quad * 4;
#pragma unroll
      for (int nbo = 0; nbo < 8; ++nbo)
#pragma unroll
        for (int r = 0; r < 4; ++r)
          atomicAdd(&txt_acc[rb + nbo * 16 + r], O[s][nbo][r] * linv[s] * 0.02f);
    }
  }
}

// ---------------------------------------------------------------------------
// K5: out GEMM (x<282) fused with txt out rows (x>=282: 64 fp32 GEMV blocks).
__global__ __launch_bounds__(256) void k_gemm_out(const u16* __restrict__ A,
                                                  const u16* __restrict__ Bt,
                                                  float* __restrict__ out,
                                                  const float* __restrict__ acc,
                                                  const float* __restrict__ wo) {
  if (blockIdx.x < 282) {
    gemm_body<1>(A, Bt, out, 512, 512, N_VID, blockIdx.x * 128, blockIdx.y * 128);
    return;
  }
  int r = (blockIdx.x - 282) * 4 + blockIdx.y;   // 0..63
  int t = threadIdx.x;
  float s0 = 0.f, s1 = 0.f;
  for (int k = 0; k < 512; ++k) {
    float a = acc[r * 512 + k];
    s0 = fmaf(a, wo[k * 512 + t], s0);
    s1 = fmaf(a, wo[k * 512 + t + 256], s1);
  }
  float* ob = out + (size_t)N_VID * DM;
  ob[(size_t)r * 512 + t] = s0;
  ob[(size_t)r * 512 + t + 256] = s1;
}

// ---------------------------------------------------------------------------
extern "C" void kernel_launch(void* const* d_in, const int* in_sizes, int n_in,
                              void* d_out, int out_size, void* d_ws, size_t ws_size,
                              hipStream_t stream) {
  const float* vid       = (const float*)d_in[0];
  const float* txt       = (const float*)d_in[1];
  const float* w_qkv_vid = (const float*)d_in[2];
  const float* w_qkv_txt = (const float*)d_in[3];
  const float* w_out_vid = (const float*)d_in[4];
  const float* w_out_txt = (const float*)d_in[5];
  float* out = (float*)d_out;
  char* ws = (char*)d_ws;

  size_t off = 0;
  u16* vid_b   = (u16*)(ws + off); off += (size_t)MPAD * DM * 2;       // reused as out_rows
  u16* txt_b   = (u16*)(ws + off); off += 128 * DM * 2;
  u16* wt_qv   = (u16*)(ws + off); off += 1536 * 512 * 2;
  u16* wt_qt   = (u16*)(ws + off); off += 1536 * 512 * 2;
  u16* wt_ov   = (u16*)(ws + off); off += 512 * 512 * 2;
  u16* qkv_v   = (u16*)(ws + off); off += (size_t)MPAD * 1536 * 2;
  u16* qkv_t   = (u16*)(ws + off); off += 128 * 1536 * 2;
  u16* Qb      = (u16*)(ws + off); off += (size_t)NW * 4 * SP * 128 * 2;
  u16* Kb      = (u16*)(ws + off); off += (size_t)NW * 4 * SP * 128 * 2;
  u16* Vtb     = (u16*)(ws + off); off += (size_t)NW * 4 * 128 * SP * 2;
  float* tacc  = (float*)(ws + off); off += 64 * 512 * 4;
  u16* out_rows = vid_b;   // alias: vid_b dead after QKV GEMM

  hipMemsetAsync(tacc, 0, 64 * 512 * 4, stream);

  k_prep<<<9504, 256, 0, stream>>>(vid, txt, vid_b, txt_b,
                                   w_qkv_vid, w_qkv_txt, w_out_vid,
                                   wt_qv, wt_qt, wt_ov);

  k_gemm_qkv<<<dim3(282, 13), 256, 0, stream>>>(vid_b, wt_qv, qkv_v,
                                                txt_b, wt_qt, qkv_t);

  k_ropegather<<<dim3(49, 50), 256, 0, stream>>>(qkv_v, qkv_t, Qb, Kb, Vtb);

  k_attn<<<1400, 256, 0, stream>>>(Qb, Kb, Vtb, out_rows, tacc);

  k_gemm_out<<<dim3(298, 4), 256, 0, stream>>>(out_rows, wt_ov, out, tacc, w_out_txt);
}